// Round 1
// baseline (606.107 us; speedup 1.0000x reference)
//
#include <hip/hip_runtime.h>
#include <math.h>

// Problem constants (from reference): B=4096, S=200, D=64, H=36
#define BB 4096
#define SS 200
#define DD 64
#define HH 36
#define NROWS (BB * SS)          // 819200 rows of the (N, 36) activation matrix
#define WB_PER_B (DD * HH)       // 2304 floats of folded weight per batch elem

// ---------------------------------------------------------------------------
// Kernel W: precompute per-b folded weights and bias (fast path only)
//   Wb[b][d][j] = W1b[d][j] - W1c[d][j] + c[b][d]*W1d[d][j]
//   base[b][j]  = b1[j] + sum_d c[b][d]*(W1a[d][j] + W1c[d][j])
// ---------------------------------------------------------------------------
__global__ __launch_bounds__(256) void k_wb(const float* __restrict__ cand,
                                            const float* __restrict__ W1,
                                            const float* __restrict__ b1,
                                            float* __restrict__ WbG,
                                            float* __restrict__ baseG) {
    int b = blockIdx.x, t = threadIdx.x;
    __shared__ float c[DD];
    if (t < DD) c[t] = cand[b * DD + t];
    __syncthreads();
    for (int e = t; e < WB_PER_B; e += 256) {
        int d = e / HH, j = e - d * HH;
        WbG[(size_t)b * WB_PER_B + e] =
            W1[(DD + d) * HH + j] - W1[(2 * DD + d) * HH + j] + c[d] * W1[(3 * DD + d) * HH + j];
    }
    if (t < HH) {
        float v = b1[t];
        for (int d = 0; d < DD; ++d)
            v += c[d] * (W1[d * HH + t] + W1[(2 * DD + d) * HH + t]);
        baseG[b * HH + t] = v;
    }
}

// ---------------------------------------------------------------------------
// Shared row-GEMM: acc[j] = base[j] + sum_d hist_row[d] * Wb[d][j]
// FAST: Wb/base from global, block-uniform index -> scalar loads.
// FB  : 3-term from raw W1 (scalar loads of W1 rows), base from LDS.
// ---------------------------------------------------------------------------
template <bool FAST>
__device__ __forceinline__ void row_gemm(float (&acc)[HH], const float* sh,
                                         const float* shC, const float* shBase,
                                         const float* __restrict__ wbp,
                                         const float* __restrict__ bp,
                                         const float* __restrict__ W1, int t) {
#pragma unroll
    for (int j = 0; j < HH; ++j) acc[j] = FAST ? bp[j] : shBase[j];
    if (t < SS) {
        for (int d = 0; d < DD; d += 4) {
            float4 r = *(const float4*)&sh[t * DD + d];
            if (FAST) {
                const float* __restrict__ w0 = wbp + d * HH;
#pragma unroll
                for (int j = 0; j < HH; ++j) acc[j] = fmaf(r.x, w0[j], acc[j]);
#pragma unroll
                for (int j = 0; j < HH; ++j) acc[j] = fmaf(r.y, w0[HH + j], acc[j]);
#pragma unroll
                for (int j = 0; j < HH; ++j) acc[j] = fmaf(r.z, w0[2 * HH + j], acc[j]);
#pragma unroll
                for (int j = 0; j < HH; ++j) acc[j] = fmaf(r.w, w0[3 * HH + j], acc[j]);
            } else {
                float4 cc = *(const float4*)&shC[d];
                float qx = r.x * cc.x, qy = r.y * cc.y, qz = r.z * cc.z, qw = r.w * cc.w;
                const float* __restrict__ wB = W1 + (DD + d) * HH;
                const float* __restrict__ wC = W1 + (2 * DD + d) * HH;
                const float* __restrict__ wD = W1 + (3 * DD + d) * HH;
#pragma unroll
                for (int j = 0; j < HH; ++j) {
                    float a = acc[j];
                    a = fmaf(r.x, wB[j], a);
                    a = fmaf(-r.x, wC[j], a);
                    a = fmaf(qx, wD[j], a);
                    a = fmaf(r.y, wB[HH + j], a);
                    a = fmaf(-r.y, wC[HH + j], a);
                    a = fmaf(qy, wD[HH + j], a);
                    a = fmaf(r.z, wB[2 * HH + j], a);
                    a = fmaf(-r.z, wC[2 * HH + j], a);
                    a = fmaf(qz, wD[2 * HH + j], a);
                    a = fmaf(r.w, wB[3 * HH + j], a);
                    a = fmaf(-r.w, wC[3 * HH + j], a);
                    a = fmaf(qw, wD[3 * HH + j], a);
                    acc[j] = a;
                }
            }
        }
    }
}

// ---------------------------------------------------------------------------
// Pass 1: per-b block computes h rows, accumulates global sum_j(h), sum_j(h^2)
//   sum_h via algebra: 200*base + (sum_s hist) @ Wb   (exact)
//   sum_h2 via LDS transpose reduction (reusing the dead hist buffer)
// ---------------------------------------------------------------------------
template <bool FAST>
__global__ __launch_bounds__(256) void k_pass1(const float* __restrict__ hist,
                                               const float* __restrict__ cand,
                                               const float* __restrict__ W1,
                                               const float* __restrict__ b1,
                                               const float* __restrict__ WbG,
                                               const float* __restrict__ baseG,
                                               float* __restrict__ gsum,
                                               float* __restrict__ gsum2) {
    int b = blockIdx.x, t = threadIdx.x;
    int wave = t >> 6, lane = t & 63;
    __shared__ float sh[SS * DD];        // 51200 B: hist tile, later sq matrix
    __shared__ float shHp[4][DD];        // per-wave hist column partials
    __shared__ float shHb[DD];           // sum_s hist[s][d]
    __shared__ float shSqp[4][HH];       // per-wave sumsq partials
    __shared__ float shC[DD];
    __shared__ float shBase[HH];

    {   // stage history tile (coalesced float4)
        const float4* src = (const float4*)(hist + (size_t)b * (SS * DD));
        float4* dst = (float4*)sh;
        for (int i = t; i < SS * DD / 4; i += 256) dst[i] = src[i];
    }
    if (!FAST) {
        if (t < DD) shC[t] = cand[b * DD + t];
    }
    __syncthreads();
    if (!FAST) {
        if (t < HH) {
            float v = b1[t];
            for (int d = 0; d < DD; ++d)
                v += shC[d] * (W1[d * HH + t] + W1[(2 * DD + d) * HH + t]);
            shBase[t] = v;
        }
        __syncthreads();
    }
    {   // history column-sum partials (each wave takes 50 rows)
        float p = 0.f;
        int s0 = wave * 50;
        for (int s = s0; s < s0 + 50; ++s) p += sh[s * DD + lane];
        shHp[wave][lane] = p;
    }
    float acc[HH];
    const float* wbp = FAST ? (WbG + (size_t)b * WB_PER_B) : nullptr;
    const float* bp = FAST ? (baseG + b * HH) : nullptr;
    row_gemm<FAST>(acc, sh, shC, shBase, wbp, bp, W1, t);
    __syncthreads();  // hist reads done; shHp complete
    if (t < DD) shHb[t] = shHp[0][t] + shHp[1][t] + shHp[2][t] + shHp[3][t];
    if (t < SS) {  // overwrite dead hist region with h^2 rows (stride HH)
        float4* sq = (float4*)&sh[t * HH];
#pragma unroll
        for (int q4 = 0; q4 < HH / 4; ++q4) {
            float4 v;
            v.x = acc[4 * q4 + 0] * acc[4 * q4 + 0];
            v.y = acc[4 * q4 + 1] * acc[4 * q4 + 1];
            v.z = acc[4 * q4 + 2] * acc[4 * q4 + 2];
            v.w = acc[4 * q4 + 3] * acc[4 * q4 + 3];
            sq[q4] = v;
        }
    }
    __syncthreads();
    if (lane < HH) {  // column partials of sq
        float p = 0.f;
        int s0 = wave * 50;
        for (int s = s0; s < s0 + 50; ++s) p += sh[s * HH + lane];
        shSqp[wave][lane] = p;
    }
    __syncthreads();
    if (t < HH) {
        float sq = shSqp[0][t] + shSqp[1][t] + shSqp[2][t] + shSqp[3][t];
        atomicAdd(gsum2 + t, sq);
        float v;
        if (FAST) {
            v = (float)SS * baseG[b * HH + t];
            const float* __restrict__ wq = WbG + (size_t)b * WB_PER_B;
            for (int d = 0; d < DD; ++d) v = fmaf(shHb[d], wq[d * HH + t], v);
        } else {
            v = (float)SS * shBase[t];
            for (int d = 0; d < DD; ++d) {
                float hb = shHb[d];
                v = fmaf(hb, W1[(DD + d) * HH + t], v);
                v = fmaf(-hb, W1[(2 * DD + d) * HH + t], v);
                v = fmaf(hb * shC[d], W1[(3 * DD + d) * HH + t], v);
            }
        }
        atomicAdd(gsum + t, v);
    }
}

// ---------------------------------------------------------------------------
// Stats: fold BN into per-feature affine  h' = h*A + Bc
// ---------------------------------------------------------------------------
__global__ void k_stats(const float* __restrict__ gsum, const float* __restrict__ gsum2,
                        const float* __restrict__ gamma, const float* __restrict__ beta,
                        float* __restrict__ A, float* __restrict__ Bc) {
    int t = threadIdx.x;
    if (t < HH) {
        float mu = gsum[t] * (1.0f / (float)NROWS);
        float var = gsum2[t] * (1.0f / (float)NROWS) - mu * mu;
        float rs = rsqrtf(var + 1e-5f);
        float a = rs * gamma[t];
        A[t] = a;
        Bc[t] = beta[t] - mu * a;
    }
}

// ---------------------------------------------------------------------------
// Pass 2: recompute h, BN affine, Dice, output linear, weighted-sum pooling
// ---------------------------------------------------------------------------
template <bool FAST>
__global__ __launch_bounds__(256) void k_pass2(const float* __restrict__ hist,
                                               const float* __restrict__ cand,
                                               const float* __restrict__ W1,
                                               const float* __restrict__ b1,
                                               const float* __restrict__ WbG,
                                               const float* __restrict__ baseG,
                                               const float* __restrict__ Acoef,
                                               const float* __restrict__ Bcoef,
                                               const float* __restrict__ alpha,
                                               const float* __restrict__ W2,
                                               const float* __restrict__ b2,
                                               float* __restrict__ out) {
    int b = blockIdx.x, t = threadIdx.x;
    int wave = t >> 6, lane = t & 63;
    __shared__ float sh[SS * DD];
    __shared__ float shW[SS];
    __shared__ float shPool[4][DD];
    __shared__ float shC[DD];
    __shared__ float shBase[HH];

    {
        const float4* src = (const float4*)(hist + (size_t)b * (SS * DD));
        float4* dst = (float4*)sh;
        for (int i = t; i < SS * DD / 4; i += 256) dst[i] = src[i];
    }
    if (!FAST) {
        if (t < DD) shC[t] = cand[b * DD + t];
    }
    __syncthreads();
    if (!FAST) {
        if (t < HH) {
            float v = b1[t];
            for (int d = 0; d < DD; ++d)
                v += shC[d] * (W1[d * HH + t] + W1[(2 * DD + d) * HH + t]);
            shBase[t] = v;
        }
        __syncthreads();
    }
    float acc[HH];
    const float* wbp = FAST ? (WbG + (size_t)b * WB_PER_B) : nullptr;
    const float* bp = FAST ? (baseG + b * HH) : nullptr;
    row_gemm<FAST>(acc, sh, shC, shBase, wbp, bp, W1, t);
    if (t < SS) {
        float alv = alpha[0];
        // BatchNorm (folded affine)
#pragma unroll
        for (int j = 0; j < HH; ++j) acc[j] = fmaf(acc[j], Acoef[j], Bcoef[j]);
        // Dice
        float s1 = 0.f, s2 = 0.f;
#pragma unroll
        for (int j = 0; j < HH; ++j) {
            s1 += acc[j];
            s2 += acc[j] * acc[j];
        }
        float avg = s1 * (1.0f / (float)HH);
        float var = s2 * (1.0f / (float)HH) - avg * avg;
        float inv = rsqrtf(var + 1e-3f);
        float w = b2[0];
#pragma unroll
        for (int j = 0; j < HH; ++j) {
            float z = (acc[j] - avg) * inv;
            float ps = 1.0f / (1.0f + __expf(-z));
            float f = alv + ps * (1.0f - alv);
            w = fmaf(acc[j] * f, W2[j], w);
        }
        shW[t] = w;
    }
    __syncthreads();
    {   // weighted-sum pooling: out[b][d] = sum_s w[s]*hist[s][d]
        float p = 0.f;
        int s0 = wave * 50;
        for (int s = s0; s < s0 + 50; ++s) p = fmaf(shW[s], sh[s * DD + lane], p);
        shPool[wave][lane] = p;
    }
    __syncthreads();
    if (t < DD)
        out[b * DD + t] = shPool[0][t] + shPool[1][t] + shPool[2][t] + shPool[3][t];
}

// ---------------------------------------------------------------------------
extern "C" void kernel_launch(void* const* d_in, const int* in_sizes, int n_in,
                              void* d_out, int out_size, void* d_ws, size_t ws_size,
                              hipStream_t stream) {
    const float* hist = (const float*)d_in[0];
    const float* cand = (const float*)d_in[1];
    const float* W1 = (const float*)d_in[2];
    const float* b1 = (const float*)d_in[3];
    const float* gamma = (const float*)d_in[4];
    const float* beta = (const float*)d_in[5];
    const float* alpha = (const float*)d_in[6];
    const float* W2 = (const float*)d_in[7];
    const float* b2 = (const float*)d_in[8];
    float* out = (float*)d_out;
    float* ws = (float*)d_ws;

    const size_t wbF = (size_t)BB * WB_PER_B;   // 9,437,184 floats
    const size_t baseF = (size_t)BB * HH;       // 147,456 floats
    const size_t needFast = (wbF + baseF + 144) * sizeof(float);  // ~38.3 MB
    bool fast = ws_size >= needFast;

    float *WbG, *baseG, *gsum, *gsum2, *A, *Bc;
    if (fast) {
        WbG = ws;
        baseG = ws + wbF;
        gsum = baseG + baseF;
        gsum2 = gsum + HH;
        A = gsum2 + HH;
        Bc = A + HH;
    } else {
        WbG = nullptr;
        baseG = nullptr;
        gsum = ws;
        gsum2 = ws + HH;
        A = ws + 2 * HH;
        Bc = ws + 3 * HH;
    }
    hipMemsetAsync(gsum, 0, 2 * HH * sizeof(float), stream);
    if (fast) {
        k_wb<<<BB, 256, 0, stream>>>(cand, W1, b1, WbG, baseG);
        k_pass1<true><<<BB, 256, 0, stream>>>(hist, cand, W1, b1, WbG, baseG, gsum, gsum2);
    } else {
        k_pass1<false><<<BB, 256, 0, stream>>>(hist, cand, W1, b1, WbG, baseG, gsum, gsum2);
    }
    k_stats<<<1, 64, 0, stream>>>(gsum, gsum2, gamma, beta, A, Bc);
    if (fast) {
        k_pass2<true><<<BB, 256, 0, stream>>>(hist, cand, W1, b1, WbG, baseG, A, Bc, alpha,
                                              W2, b2, out);
    } else {
        k_pass2<false><<<BB, 256, 0, stream>>>(hist, cand, W1, b1, WbG, baseG, A, Bc, alpha,
                                               W2, b2, out);
    }
}

// Round 2
// 475.355 us; speedup vs baseline: 1.2751x; 1.2751x over previous
//
#include <hip/hip_runtime.h>
#include <math.h>

// B=4096, S=200, D=64, H=36
#define BB 4096
#define SS 200
#define DD 64
#define HH 36
#define NP 48           // H padded to 3 n-tiles of 16
#define NROWS (BB * SS)
#define LDH 72          // LDS row stride in bf16 units (64 + 8 pad -> conflict-free b128)
#define MT 13           // ceil(200/16) m-tiles

typedef short bf16x8 __attribute__((ext_vector_type(8)));
typedef float f32x4 __attribute__((ext_vector_type(4)));

__device__ __forceinline__ unsigned short f2bf(float f) {
    union { float f; unsigned u; } v; v.f = f;
    unsigned r = v.u + 0x7FFFu + ((v.u >> 16) & 1u);   // RNE
    return (unsigned short)(r >> 16);
}

// ---------------------------------------------------------------------------
// Shared prologue: stage hist (fp32->bf16, padded), build folded WbT + base.
//   Wb[k][j] = W1b[k][j] - W1c[k][j] + c[k]*W1d[k][j]   (stored transposed [n][k])
//   base[j]  = b1[j] + sum_k c[k]*(W1a[k][j] + W1c[k][j])
// ---------------------------------------------------------------------------
__device__ __forceinline__ void build_tiles(int b, int t,
                                            const float* __restrict__ hist,
                                            const float* __restrict__ cand,
                                            const float* __restrict__ W1,
                                            const float* __restrict__ b1,
                                            unsigned short* shH, unsigned short* shWbT,
                                            float* shC, float* shBase,
                                            float (*shBaseP)[NP]) {
    if (t < DD) shC[t] = cand[b * DD + t];
    // zero pad rows 200..207 (k-cols 0..63 are all frag reads touch)
    for (int i = t; i < 8 * DD; i += 256) {
        int s = SS + (i >> 6), d = i & 63;
        shH[s * LDH + d] = 0;
    }
    __syncthreads();
    // hist tile: coalesced float4 global reads -> bf16x4 LDS writes
    const float4* src = (const float4*)(hist + (size_t)b * (SS * DD));
    for (int i = t; i < SS * DD / 4; i += 256) {
        float4 v = src[i];
        int s = i >> 4, c = i & 15;
        ushort4 o;
        o.x = f2bf(v.x); o.y = f2bf(v.y); o.z = f2bf(v.z); o.w = f2bf(v.w);
        *(ushort4*)&shH[s * LDH + c * 4] = o;
    }
    // WbT[n][k] (bf16), pad n>=36 -> 0
    for (int e = t; e < NP * DD; e += 256) {
        int k = e / NP, n = e - k * NP;
        float v = 0.f;
        if (n < HH)
            v = W1[(DD + k) * HH + n] - W1[(2 * DD + k) * HH + n] +
                shC[k] * W1[(3 * DD + k) * HH + n];
        shWbT[n * LDH + k] = f2bf(v);
    }
    // base partials: 4 groups of 16 k's
    if (t < 4 * NP) {
        int g = t / NP, j = t - g * NP;
        float p = 0.f;
        if (j < HH) {
#pragma unroll 4
            for (int k = 16 * g; k < 16 * g + 16; ++k)
                p += shC[k] * (W1[k * HH + j] + W1[(2 * DD + k) * HH + j]);
        }
        shBaseP[g][j] = p;
    }
    __syncthreads();
    if (t < NP) {
        float v = (t < HH) ? b1[t] : 0.f;
        shBase[t] = v + shBaseP[0][t] + shBaseP[1][t] + shBaseP[2][t] + shBaseP[3][t];
    }
    __syncthreads();
}

__device__ __forceinline__ void load_bfrags(const unsigned short* shWbT, int lane,
                                            bf16x8 (&bfr)[3][2]) {
    int col = lane & 15, q = lane >> 4;
#pragma unroll
    for (int nt = 0; nt < 3; ++nt)
#pragma unroll
        for (int kt = 0; kt < 2; ++kt)
            bfr[nt][kt] = *(const bf16x8*)&shWbT[(nt * 16 + col) * LDH + kt * 32 + q * 8];
}

__device__ __forceinline__ void gemm_tile(const unsigned short* shH,
                                          const bf16x8 (&bfr)[3][2], int mt, int lane,
                                          f32x4 (&d)[3]) {
    int m = mt * 16 + (lane & 15), q = lane >> 4;
    d[0] = f32x4{0.f, 0.f, 0.f, 0.f};
    d[1] = f32x4{0.f, 0.f, 0.f, 0.f};
    d[2] = f32x4{0.f, 0.f, 0.f, 0.f};
#pragma unroll
    for (int kt = 0; kt < 2; ++kt) {
        bf16x8 a = *(const bf16x8*)&shH[m * LDH + kt * 32 + q * 8];
#pragma unroll
        for (int nt = 0; nt < 3; ++nt)
            d[nt] = __builtin_amdgcn_mfma_f32_16x16x32_bf16(a, bfr[nt][kt], d[nt], 0, 0, 0);
    }
}

// ---------------------------------------------------------------------------
// Pass 1: column sums of h and h^2 (BN batch statistics)
// ---------------------------------------------------------------------------
__global__ __launch_bounds__(256, 4) void k_pass1(const float* __restrict__ hist,
                                                  const float* __restrict__ cand,
                                                  const float* __restrict__ W1,
                                                  const float* __restrict__ b1,
                                                  float* __restrict__ gsum,
                                                  float* __restrict__ gsum2) {
    __shared__ unsigned short shH[208 * LDH];
    __shared__ unsigned short shWbT[NP * LDH];
    __shared__ float shC[DD], shBase[NP];
    __shared__ float shBaseP[4][NP];
    __shared__ float shP1[4][NP], shP2[4][NP];
    int b = blockIdx.x, t = threadIdx.x, wave = t >> 6, lane = t & 63;
    int col = lane & 15, q = lane >> 4;

    build_tiles(b, t, hist, cand, W1, b1, shH, shWbT, shC, shBase, shBaseP);

    bf16x8 bfr[3][2];
    load_bfrags(shWbT, lane, bfr);
    float basev[3];
#pragma unroll
    for (int nt = 0; nt < 3; ++nt) basev[nt] = shBase[nt * 16 + col];

    float cs1[3] = {0.f, 0.f, 0.f}, cs2[3] = {0.f, 0.f, 0.f};
    for (int mt = wave; mt < MT; mt += 4) {
        f32x4 d[3];
        gemm_tile(shH, bfr, mt, lane, d);
        int row0 = mt * 16 + q * 4;
#pragma unroll
        for (int nt = 0; nt < 3; ++nt)
#pragma unroll
            for (int r = 0; r < 4; ++r) {
                if (row0 + r < SS) {
                    float v = d[nt][r] + basev[nt];
                    cs1[nt] += v;
                    cs2[nt] += v * v;
                }
            }
    }
    // reduce across the 4 quads
#pragma unroll
    for (int nt = 0; nt < 3; ++nt) {
        cs1[nt] += __shfl_xor(cs1[nt], 16);
        cs1[nt] += __shfl_xor(cs1[nt], 32);
        cs2[nt] += __shfl_xor(cs2[nt], 16);
        cs2[nt] += __shfl_xor(cs2[nt], 32);
    }
    if (lane < 16) {
#pragma unroll
        for (int nt = 0; nt < 3; ++nt) {
            shP1[wave][nt * 16 + lane] = cs1[nt];
            shP2[wave][nt * 16 + lane] = cs2[nt];
        }
    }
    __syncthreads();
    if (t < HH) {
        atomicAdd(gsum + t, shP1[0][t] + shP1[1][t] + shP1[2][t] + shP1[3][t]);
        atomicAdd(gsum2 + t, shP2[0][t] + shP2[1][t] + shP2[2][t] + shP2[3][t]);
    }
}

// ---------------------------------------------------------------------------
// Stats: fold BN into per-feature affine (pads zeroed)
// ---------------------------------------------------------------------------
__global__ void k_stats(const float* __restrict__ gsum, const float* __restrict__ gsum2,
                        const float* __restrict__ gamma, const float* __restrict__ beta,
                        float* __restrict__ A, float* __restrict__ Bc) {
    int t = threadIdx.x;
    if (t < NP) {
        if (t < HH) {
            float mu = gsum[t] * (1.0f / (float)NROWS);
            float var = gsum2[t] * (1.0f / (float)NROWS) - mu * mu;
            float rs = rsqrtf(var + 1e-5f);
            float a = rs * gamma[t];
            A[t] = a;
            Bc[t] = beta[t] - mu * a;
        } else {
            A[t] = 0.f;
            Bc[t] = 0.f;
        }
    }
}

// ---------------------------------------------------------------------------
// Pass 2: h -> BN affine -> Dice -> output linear -> weighted-sum pooling
// ---------------------------------------------------------------------------
__global__ __launch_bounds__(256, 4) void k_pass2(const float* __restrict__ hist,
                                                  const float* __restrict__ cand,
                                                  const float* __restrict__ W1,
                                                  const float* __restrict__ b1,
                                                  const float* __restrict__ Acoef,
                                                  const float* __restrict__ Bcoef,
                                                  const float* __restrict__ alpha,
                                                  const float* __restrict__ W2,
                                                  const float* __restrict__ b2,
                                                  float* __restrict__ out) {
    __shared__ unsigned short shH[208 * LDH];
    __shared__ unsigned short shWbT[NP * LDH];
    __shared__ float shC[DD], shBase[NP];
    __shared__ float shBaseP[4][NP];
    __shared__ float shW[208];
    __shared__ float shPool[4][DD];
    int b = blockIdx.x, t = threadIdx.x, wave = t >> 6, lane = t & 63;
    int col = lane & 15, q = lane >> 4;

    build_tiles(b, t, hist, cand, W1, b1, shH, shWbT, shC, shBase, shBaseP);

    bf16x8 bfr[3][2];
    load_bfrags(shWbT, lane, bfr);
    float basev[3], Ar[3], Br[3], W2r[3];
#pragma unroll
    for (int nt = 0; nt < 3; ++nt) {
        int c = nt * 16 + col;
        basev[nt] = shBase[c];
        Ar[nt] = Acoef[c];
        Br[nt] = Bcoef[c];
        W2r[nt] = (c < HH) ? W2[c] : 0.f;
    }
    float alv = alpha[0], b2v = b2[0];

    for (int mt = wave; mt < MT; mt += 4) {
        f32x4 d[3];
        gemm_tile(shH, bfr, mt, lane, d);
        float hp[3][4];
#pragma unroll
        for (int nt = 0; nt < 3; ++nt)
#pragma unroll
            for (int r = 0; r < 4; ++r)
                hp[nt][r] = fmaf(d[nt][r] + basev[nt], Ar[nt], Br[nt]);
        float s1[4], s2[4], wsum[4];
#pragma unroll
        for (int r = 0; r < 4; ++r) {
            s1[r] = hp[0][r] + hp[1][r] + hp[2][r];
            s2[r] = hp[0][r] * hp[0][r] + hp[1][r] * hp[1][r] + hp[2][r] * hp[2][r];
            s1[r] += __shfl_xor(s1[r], 1);
            s1[r] += __shfl_xor(s1[r], 2);
            s1[r] += __shfl_xor(s1[r], 4);
            s1[r] += __shfl_xor(s1[r], 8);
            s2[r] += __shfl_xor(s2[r], 1);
            s2[r] += __shfl_xor(s2[r], 2);
            s2[r] += __shfl_xor(s2[r], 4);
            s2[r] += __shfl_xor(s2[r], 8);
        }
#pragma unroll
        for (int r = 0; r < 4; ++r) {
            float avg = s1[r] * (1.0f / (float)HH);
            float var = s2[r] * (1.0f / (float)HH) - avg * avg;
            float inv = rsqrtf(var + 1e-3f);
            float wv = 0.f;
#pragma unroll
            for (int nt = 0; nt < 3; ++nt) {
                float z = (hp[nt][r] - avg) * inv;
                float ps = 1.0f / (1.0f + __expf(-z));
                float f = ps + (1.0f - ps) * alv;   // ps*h + (1-ps)*alpha*h
                wv = fmaf(hp[nt][r] * f, W2r[nt], wv);
            }
            wsum[r] = wv;
            wsum[r] += __shfl_xor(wsum[r], 1);
            wsum[r] += __shfl_xor(wsum[r], 2);
            wsum[r] += __shfl_xor(wsum[r], 4);
            wsum[r] += __shfl_xor(wsum[r], 8);
        }
        if (col == 0 && !(mt == MT - 1 && q >= 2)) {
            float4 o = {wsum[0] + b2v, wsum[1] + b2v, wsum[2] + b2v, wsum[3] + b2v};
            *(float4*)&shW[mt * 16 + q * 4] = o;
        }
    }
    __syncthreads();
    // pooling: out[b][d] = sum_s w[s]*hist[s][d]  (fp32 from global, L2-hot)
    {
        const float* hb = hist + (size_t)b * SS * DD;
        float p = 0.f;
        int s0 = wave * 50;
        for (int s = s0; s < s0 + 50; ++s) p = fmaf(shW[s], hb[(size_t)s * DD + lane], p);
        shPool[wave][lane] = p;
    }
    __syncthreads();
    if (t < DD)
        out[b * DD + t] = shPool[0][t] + shPool[1][t] + shPool[2][t] + shPool[3][t];
}

// ---------------------------------------------------------------------------
extern "C" void kernel_launch(void* const* d_in, const int* in_sizes, int n_in,
                              void* d_out, int out_size, void* d_ws, size_t ws_size,
                              hipStream_t stream) {
    const float* hist = (const float*)d_in[0];
    const float* cand = (const float*)d_in[1];
    const float* W1 = (const float*)d_in[2];
    const float* b1 = (const float*)d_in[3];
    const float* gamma = (const float*)d_in[4];
    const float* beta = (const float*)d_in[5];
    const float* alpha = (const float*)d_in[6];
    const float* W2 = (const float*)d_in[7];
    const float* b2 = (const float*)d_in[8];
    float* out = (float*)d_out;
    float* ws = (float*)d_ws;

    float* gsum = ws;            // 48
    float* gsum2 = ws + NP;      // 48
    float* A = ws + 2 * NP;      // 48
    float* Bc = ws + 3 * NP;     // 48

    hipMemsetAsync(gsum, 0, 2 * NP * sizeof(float), stream);
    k_pass1<<<BB, 256, 0, stream>>>(hist, cand, W1, b1, gsum, gsum2);
    k_stats<<<1, 64, 0, stream>>>(gsum, gsum2, gamma, beta, A, Bc);
    k_pass2<<<BB, 256, 0, stream>>>(hist, cand, W1, b1, A, Bc, alpha, W2, b2, out);
}